// Round 14
// baseline (327.159 us; speedup 1.0000x reference)
//
#include <hip/hip_runtime.h>
#include <hip/hip_bf16.h>
#include <stdint.h>
#include <stddef.h>

typedef __bf16 bf16;
typedef float f32x4 __attribute__((ext_vector_type(4)));
typedef bf16 bf16x8 __attribute__((ext_vector_type(8)));
typedef bf16 bf16x4 __attribute__((ext_vector_type(4)));

#define MROWS 8192
#define NOUT 256
#define BK 128
#define NTHREADS 512
#define LDS_SMALL (32 * BK * 2)

#define SCHED0 __builtin_amdgcn_sched_barrier(0)
#define SBAR __builtin_amdgcn_s_barrier()

// ---------------------------------------------------------------------------
// Bp fragment-permuted layout: for K-step ts, wave w, frag (bfi,ak), lane l,
// 16B chunk at byte (ts*64 + w*8 + bfi*4 + ak)*1024 + l*16, holding
// B[n][k0..k0+7], n = w*32+bfi*16+(l&15), k0 = ts*128+ak*32+(l>>4)*8.
// Producer map (n,k): ts=k>>7, w=n>>5, bfi=(n>>4)&1, ak=(k>>5)&3,
//   l=((k>>3)&3)*16+(n&15), byte=(k&7)*2.
// ---------------------------------------------------------------------------

// ================= K-split big GEMM: BM=128, fp32 partial output =============
// grid = 64 mtiles x KS kslices. Each block reads 1/KS of Bp -> chip B traffic
// = 256MB/KS instead of 1GB. Partial slice ks==KS-1 goes to doutP.
__global__ __launch_bounds__(NTHREADS, 1) void gemm_ks(
    const float* __restrict__ A, const bf16* __restrict__ Bp,
    float* __restrict__ wsP, float* __restrict__ doutP,
    const int kshift, const int nsteps, const int lda) {
  __shared__ char lds[2][32768];
  const int t = threadIdx.x;
  const int w = t >> 6;
  const int l = t & 63;
  const int ks = blockIdx.x & ((1 << kshift) - 1);
  const int mt = blockIdx.x >> kshift;
  const int m0 = mt * 128;
  const int ts0 = ks * nsteps;
  float* __restrict__ Ps =
      (ks == ((1 << kshift) - 1)) ? doutP : wsP + (size_t)ks * 2097152;

  // A staging: op q (0..7): row m0 + w*16 + q*2 + (l>>5), float col
  // ts0*128 + s*128 + (l&31)*4  (two dense 512B segments per wave-op)
  const float* gAq[8];
#pragma unroll
  for (int q = 0; q < 8; ++q)
    gAq[q] = A + (size_t)(m0 + w * 16 + q * 2 + (l >> 5)) * (size_t)lda +
             (size_t)ts0 * BK + (l & 31) * 4;

  // LDS slot layout: [128 rows][256B], elem (r, kf) at r*256 + ((kf*2)^((r&7)<<4))
  int awoff[8];
#pragma unroll
  for (int q = 0; q < 8; ++q) {
    const int r = w * 16 + q * 2 + (l >> 5);
    awoff[q] = r * 256 + ((((l & 31) * 8)) ^ ((r & 7) << 4));
  }

  int aoff[8][4];
#pragma unroll
  for (int af = 0; af < 8; ++af)
#pragma unroll
    for (int ak = 0; ak < 4; ++ak) {
      const int r = af * 16 + (l & 15);
      aoff[af][ak] = r * 256 + ((ak * 64 + (l >> 4) * 16) ^ ((r & 7) << 4));
    }

  const char* pBw = (const char*)Bp + w * 8192 + l * 16;

  f32x4 acc[8][2] = {};
  f32x4 pA[8];
  bf16x8 Breg[2][2][4];

  // ---------------- prologue ----------------
#pragma unroll
  for (int q = 0; q < 8; ++q) pA[q] = __builtin_nontemporal_load((const f32x4*)gAq[q]);
  SCHED0;
#pragma unroll
  for (int bfi = 0; bfi < 2; ++bfi)
#pragma unroll
    for (int ak = 0; ak < 4; ++ak)
      Breg[0][bfi][ak] = *(const bf16x8*)(pBw + ((size_t)ts0 << 16) +
                                          (bfi * 4 + ak) * 1024);
  SCHED0;
#pragma unroll
  for (int q = 0; q < 8; ++q) {
    bf16x4 pk;
#pragma unroll
    for (int e = 0; e < 4; ++e) pk[e] = (bf16)pA[q][e];
    *(bf16x4*)(lds[0] + awoff[q]) = pk;
  }
  SCHED0;
  {
    const int s1 = (nsteps > 1) ? 1 : 0;
#pragma unroll
    for (int q = 0; q < 8; ++q)
      pA[q] = __builtin_nontemporal_load((const f32x4*)(gAq[q] + s1 * BK));
  }
  asm volatile("s_waitcnt lgkmcnt(0)" ::: "memory");
  SBAR;
  SCHED0;

  // ---------------- main loop ----------------
  for (int s = 0; s < nsteps; ++s) {
    const char* rslot = lds[s & 1];
    char* wslot = lds[(s + 1) & 1];
    // 1. ds_write A(s+1) (pA loaded last iteration; slot freed by prev barrier)
#pragma unroll
    for (int q = 0; q < 8; ++q) {
      bf16x4 pk;
#pragma unroll
      for (int e = 0; e < 4; ++e) pk[e] = (bf16)pA[q][e];
      *(bf16x4*)(wslot + awoff[q]) = pk;
    }
    SCHED0;
    // 2. B(s+1) prefetch (consumed next step; L2-resident slice)
    {
      const int tn = (s + 1 < nsteps) ? ts0 + s + 1 : ts0;
#pragma unroll
      for (int bfi = 0; bfi < 2; ++bfi)
#pragma unroll
        for (int ak = 0; ak < 4; ++ak)
          Breg[(s + 1) & 1][bfi][ak] = *(const bf16x8*)(
              pBw + ((size_t)tn << 16) + (bfi * 4 + ak) * 1024);
    }
    SCHED0;
    // 3. A(s+2) loads (used for ds_write next iteration)
    {
      const int ka = (s + 2 < nsteps) ? (s + 2) * BK : 0;
#pragma unroll
      for (int q = 0; q < 8; ++q)
        pA[q] = __builtin_nontemporal_load((const f32x4*)(gAq[q] + ka));
    }
    SCHED0;
    // 4. MFMA (64/wave), per-ak fragment reads
    __builtin_amdgcn_s_setprio(1);
#pragma unroll
    for (int ak = 0; ak < 4; ++ak) {
      bf16x8 afr[8];
#pragma unroll
      for (int af = 0; af < 8; ++af)
        afr[af] = *(const bf16x8*)(rslot + aoff[af][ak]);
#pragma unroll
      for (int af = 0; af < 8; ++af)
#pragma unroll
        for (int bfi = 0; bfi < 2; ++bfi)
          acc[af][bfi] = __builtin_amdgcn_mfma_f32_16x16x32_bf16(
              afr[af], Breg[s & 1][bfi][ak], acc[af][bfi], 0, 0, 0);
    }
    __builtin_amdgcn_s_setprio(0);
    SCHED0;
    asm volatile("s_waitcnt lgkmcnt(0)" ::: "memory");
    SBAR;
    SCHED0;
  }

  // ---------------- epilogue: fp32 partial [8192][256] ----------------
#pragma unroll
  for (int af = 0; af < 8; ++af)
#pragma unroll
    for (int bfi = 0; bfi < 2; ++bfi) {
      const int mb = m0 + af * 16 + (l >> 4) * 4;
      const int n = w * 32 + bfi * 16 + (l & 15);
#pragma unroll
      for (int j = 0; j < 4; ++j)
        Ps[(size_t)(mb + j) * NOUT + n] = acc[af][bfi][j];
    }
}

// reduce2: Fp[m][n] (Bp layout bf16) = filt[m] * sum_ks P[ks][m][n]
__global__ void reduce2(const float* __restrict__ wsP,
                        const float* __restrict__ doutP,
                        const float* __restrict__ filt, bf16* __restrict__ Fp,
                        const int KS) {
  const int n = threadIdx.x;
  const int m8 = blockIdx.x;  // 1024 blocks, 8 rows each
  bf16x8 pk;
#pragma unroll
  for (int r = 0; r < 8; ++r) {
    const int m = m8 * 8 + r;
    float s = doutP[(size_t)m * NOUT + n];
    for (int ks = 0; ks < KS - 1; ++ks)
      s += wsP[(size_t)ks * 2097152 + (size_t)m * NOUT + n];
    pk[r] = (bf16)(s * filt[m]);
  }
  const int ts = m8 >> 4, wq = n >> 5, bq = (n >> 4) & 1, aq = (m8 >> 2) & 3;
  const int lq = (m8 & 3) * 16 + (n & 15);
  *(bf16x8*)((char*)Fp +
             (size_t)(((ts * 64 + wq * 8 + bq * 4 + aq) << 10) + lq * 16)) = pk;
}

// reduce3: doutP[i] = sum_ks P[ks][i]
__global__ void reduce3(const float* __restrict__ wsP, float* __restrict__ doutP,
                        const int KS) {
  const size_t i = (size_t)blockIdx.x * 256 + threadIdx.x;
  float s = doutP[i];
  for (int ks = 0; ks < KS - 1; ++ks) s += wsP[(size_t)ks * 2097152 + i];
  doutP[i] = s;
}

// ======================= small-K kernel (round-4 schedule) ==================
template <bool SCALE, bool OUTT>
__global__ __launch_bounds__(NTHREADS, 1) void gemm_small(
    const float* __restrict__ A, const bf16* __restrict__ Bp,
    const float* __restrict__ filt, void* __restrict__ outp,
    const int K, const int lda) {
  __shared__ char lds[2][LDS_SMALL];
  const int t = threadIdx.x;
  const int w = t >> 6;
  const int l = t & 63;
  const int m0 = blockIdx.x * 32;
  const int NT = K / BK;

  const int ar = t >> 4;
  const int acb = t & 15;
  const float* gA = A + (size_t)(m0 + ar) * (size_t)lda + acb * 8;
  const int a_lds_off = (ar * (BK * 2) + acb * 16) ^ ((ar & 7) << 4);

  int aoff[2][4];
#pragma unroll
  for (int af = 0; af < 2; ++af)
#pragma unroll
    for (int ak = 0; ak < 4; ++ak) {
      const int r = af * 16 + (l & 15);
      const int kb = ak * 64 + (l >> 4) * 16;
      aoff[af][ak] = (r * (BK * 2) + kb) ^ ((r & 7) << 4);
    }

  const char* pBw = (const char*)Bp + w * 8192 + l * 16;

  f32x4 acc[2][2] = {};

  f32x4 aS0a = __builtin_nontemporal_load((const f32x4*)gA);
  f32x4 aS0b = __builtin_nontemporal_load((const f32x4*)gA + 1);
  f32x4 aS1a = __builtin_nontemporal_load((const f32x4*)(gA + BK));
  f32x4 aS1b = __builtin_nontemporal_load((const f32x4*)(gA + BK) + 1);
  bf16x8 Bc[2][4], Bn[2][4];
#pragma unroll
  for (int bfi = 0; bfi < 2; ++bfi)
#pragma unroll
    for (int ak = 0; ak < 4; ++ak)
      Bc[bfi][ak] = *(const bf16x8*)(pBw + (bfi * 4 + ak) * 1024);
  {
    bf16x8 pk;
#pragma unroll
    for (int j = 0; j < 4; ++j) { pk[j] = (bf16)aS0a[j]; pk[j + 4] = (bf16)aS0b[j]; }
    *(bf16x8*)(lds[0] + a_lds_off) = pk;
  }
  asm volatile("s_waitcnt lgkmcnt(0)" ::: "memory");
  SBAR;
  SCHED0;

#define BODY_S(TS, P, BCUR, BNXT, AW0, AW1, AL0, AL1)                         \
  {                                                                           \
    const char* bb = lds[P];                                                  \
    bf16x8 afr[2][4];                                                         \
    _Pragma("unroll") for (int af = 0; af < 2; ++af)                          \
        _Pragma("unroll") for (int ak = 0; ak < 4; ++ak)                      \
            afr[af][ak] = *(const bf16x8*)(bb + aoff[af][ak]);                \
    SCHED0;                                                                   \
    const size_t kb1 = (size_t)((((TS) + 1) < NT ? ((TS) + 1) : 0)) << 16;    \
    _Pragma("unroll") for (int bfi = 0; bfi < 2; ++bfi)                       \
        _Pragma("unroll") for (int ak = 0; ak < 4; ++ak)                      \
            BNXT[bfi][ak] =                                                   \
                *(const bf16x8*)(pBw + kb1 + (bfi * 4 + ak) * 1024);          \
    SCHED0;                                                                   \
    const int ka2 = (((TS) + 2) < NT ? ((TS) + 2) : 0) * BK;                  \
    AL0 = __builtin_nontemporal_load((const f32x4*)(gA + ka2));               \
    AL1 = __builtin_nontemporal_load((const f32x4*)(gA + ka2) + 1);           \
    SCHED0;                                                                   \
    asm volatile("s_waitcnt lgkmcnt(0)" ::: "memory");                        \
    SCHED0;                                                                   \
    __builtin_amdgcn_s_setprio(1);                                            \
    _Pragma("unroll") for (int ak = 0; ak < 4; ++ak)                          \
        _Pragma("unroll") for (int af = 0; af < 2; ++af)                      \
            _Pragma("unroll") for (int bfi = 0; bfi < 2; ++bfi)               \
                acc[af][bfi] = __builtin_amdgcn_mfma_f32_16x16x32_bf16(       \
                    afr[af][ak], BCUR[bfi][ak], acc[af][bfi], 0, 0, 0);       \
    __builtin_amdgcn_s_setprio(0);                                            \
    SCHED0;                                                                   \
    {                                                                         \
      bf16x8 pk;                                                              \
      _Pragma("unroll") for (int j = 0; j < 4; ++j) {                         \
        pk[j] = (bf16)AW0[j];                                                 \
        pk[j + 4] = (bf16)AW1[j];                                             \
      }                                                                       \
      *(bf16x8*)(lds[P ^ 1] + a_lds_off) = pk;                                \
    }                                                                         \
    asm volatile("s_waitcnt lgkmcnt(0)" ::: "memory");                        \
    SBAR;                                                                     \
    SCHED0;                                                                   \
  }

  for (int ts = 0; ts < NT; ts += 2) {
    BODY_S(ts, 0, Bc, Bn, aS1a, aS1b, aS0a, aS0b);
    BODY_S(ts + 1, 1, Bn, Bc, aS0a, aS0b, aS1a, aS1b);
  }
#undef BODY_S

#pragma unroll
  for (int af = 0; af < 2; ++af)
#pragma unroll
    for (int bfi = 0; bfi < 2; ++bfi) {
      const int mb = m0 + af * 16 + (l >> 4) * 4;
      const int n = w * 32 + bfi * 16 + (l & 15);
      f32x4 v = acc[af][bfi];
      if (SCALE) {
#pragma unroll
        for (int j = 0; j < 4; ++j) v[j] *= filt[mb + j];
      }
      if (OUTT) {
        bf16x4 pv;
#pragma unroll
        for (int j = 0; j < 4; ++j) pv[j] = (bf16)v[j];
        const int tsq = mb >> 7, wq = n >> 5, bq = (n >> 4) & 1, aq = (mb >> 5) & 3;
        const int lq = ((mb >> 3) & 3) * 16 + (n & 15);
        char* dst = (char*)outp +
                    (size_t)(((tsq * 64 + wq * 8 + bq * 4 + aq) << 10) + lq * 16 +
                             (mb & 7) * 2);
        *(bf16x4*)dst = pv;
      } else {
        float* po = (float*)outp + (size_t)mb * NOUT + n;
#pragma unroll
        for (int j = 0; j < 4; ++j) po[(size_t)j * NOUT] = v[j];
      }
    }
}

// W [256 k][256 n] fp32 -> Wp bf16 in Bp layout
__global__ void prep_wt(const float* __restrict__ W, bf16* __restrict__ Wp) {
  const int k = blockIdx.x;
  const int n = threadIdx.x;
  const int off = (((k >> 7) * 64 + (n >> 5) * 8 + ((n >> 4) & 1) * 4 +
                    ((k >> 5) & 3)) << 10) +
                  (((k >> 3) & 3) * 16 + (n & 15)) * 16 + (k & 7) * 2;
  *(bf16*)((char*)Wp + off) = (bf16)W[k * 256 + n];
}

extern "C" void kernel_launch(void* const* d_in, const int* in_sizes, int n_in,
                              void* d_out, int out_size, void* d_ws, size_t ws_size,
                              hipStream_t stream) {
  const float* features = (const float*)d_in[0];
  const float* wavelets = (const float*)d_in[1];
  const float* wavelets_inv = (const float*)d_in[2];
  const float* W = (const float*)d_in[3];
  const float* filt = (const float*)d_in[4];
  float* out = (float*)d_out;

  char* ws = (char*)d_ws;
  bf16* Wp = (bf16*)ws;                       // 128 KiB
  bf16* Tp = (bf16*)(ws + 131072);            // 4 MiB
  bf16* Fp = (bf16*)(ws + 131072 + 4194304);  // 4 MiB
  float* wsP = (float*)(ws + 131072 + 8388608);  // up to 24 MiB of partials

  const size_t base = 131072 + 8388608;
  int KS = 0, kshift = 0;
  if (ws_size >= base + 3u * 8388608u) { KS = 4; kshift = 2; }
  else if (ws_size >= base + 1u * 8388608u) { KS = 2; kshift = 1; }

  prep_wt<<<256, 256, 0, stream>>>(W, Wp);
  gemm_small<false, true><<<256, NTHREADS, 0, stream>>>(features, Wp, nullptr, Tp, 256, 256);

  if (KS) {
    const int nsteps = 64 / KS;
    // spectral partials = wavelets_inv @ T
    gemm_ks<<<64 * KS, NTHREADS, 0, stream>>>(wavelets_inv, Tp, wsP, out, kshift, nsteps, 8192);
    // Fp = filt * sum(partials), Bp layout
    reduce2<<<1024, 256, 0, stream>>>(wsP, out, filt, Fp, KS);
    // out partials = wavelets @ F
    gemm_ks<<<64 * KS, NTHREADS, 0, stream>>>(wavelets, Fp, wsP, out, kshift, nsteps, 8192);
    // out = sum(partials)
    reduce3<<<8192, 256, 0, stream>>>(wsP, out, KS);
  } else {
    // ws too small: single-slice path (KS=1): partial == final for each GEMM
    gemm_ks<<<64, NTHREADS, 0, stream>>>(wavelets_inv, Tp, wsP, out, 0, 64, 8192);
    reduce2<<<1024, 256, 0, stream>>>(wsP, out, filt, Fp, 1);
    gemm_ks<<<64, NTHREADS, 0, stream>>>(wavelets, Fp, wsP, out, 0, 64, 8192);
  }
}

// Round 15
// 160.196 us; speedup vs baseline: 2.0422x; 2.0422x over previous
//
#include <hip/hip_runtime.h>
#include <hip/hip_bf16.h>
#include <stdint.h>
#include <stddef.h>

typedef __bf16 bf16;
typedef float f32x4 __attribute__((ext_vector_type(4)));
typedef bf16 bf16x8 __attribute__((ext_vector_type(8)));
typedef bf16 bf16x4 __attribute__((ext_vector_type(4)));

#define MROWS 8192
#define NOUT 256
#define BK 128
#define NTHREADS 512
#define LDS_SMALL (32 * BK * 2)

#define SCHED0 __builtin_amdgcn_sched_barrier(0)
#define SBAR __builtin_amdgcn_s_barrier()

// ---------------------------------------------------------------------------
// Bp fragment-permuted layout: for K-step ts, wave w, frag (bfi,ak), lane l,
// 16B chunk at byte (ts*64 + w*8 + bfi*4 + ak)*1024 + l*16, holding
// B[n][k0..k0+7], n = w*32+bfi*16+(l&15), k0 = ts*128+ak*32+(l>>4)*8.
// Producer map (n,k): ts=k>>7, w=n>>5, bfi=(n>>4)&1, ak=(k>>5)&3,
//   l=((k>>3)&3)*16+(n&15), byte=(k&7)*2.
// ---------------------------------------------------------------------------

// ================= K-split big GEMM: BM=128, fp32 partial output =============
// grid = 64 mtiles x KS kslices, bid = mt*KS + ks  ->  XCD x owns ks = x%KS
// (its 1MB B-slice is L2-resident). All register arrays statically indexed
// (rule #20): main loop unrolled x2 with named B-sets Ba/Bb.
__global__ __launch_bounds__(NTHREADS, 1) void gemm_ks(
    const float* __restrict__ A, const bf16* __restrict__ Bp,
    float* __restrict__ wsP, float* __restrict__ doutP,
    const int kshift, const int nsteps, const int lda) {
  __shared__ char lds[2][32768];
  const int t = threadIdx.x;
  const int w = t >> 6;
  const int l = t & 63;
  const int ks = blockIdx.x & ((1 << kshift) - 1);
  const int mt = blockIdx.x >> kshift;
  const int m0 = mt * 128;
  const int ts0 = ks * nsteps;
  float* __restrict__ Ps =
      (ks == ((1 << kshift) - 1)) ? doutP : wsP + (size_t)ks * 2097152;

  // A staging: op q (0..7): row m0 + w*16 + q*2 + (l>>5), float col
  // ts0*128 + s*128 + (q&1)*... -> 4 row pointers + (q&1)*1024B literal offset
  const float* gAr[4];
#pragma unroll
  for (int j = 0; j < 4; ++j)
    gAr[j] = A + (size_t)(m0 + w * 16 + j * 2 + (l >> 5)) * (size_t)lda +
             (size_t)ts0 * BK + (l & 31) * 4;
  // NOTE: q maps as row j=q>>1? No: rows are w*16 + q*2 + (l>>5) for q=0..7.
  // Rewritten: 8 ops = 4 row-pairs? rows differ per q. Use 8 rows: q*2 step.
  // gAr[j] covers rows w*16 + j*2 + (l>>5) (j=0..3) -> ops q=2j (+0 floats)
  // and q=2j+1 (+... same row? NO.
  // Correct mapping: round-14 had op q -> row w*16+q*2+(l>>5), col (l&31)*4,
  // single f32x4 per op, 8 rows total per thread? rows w*16+0..7*2+(l>>5):
  // 8 distinct rows, one f32x4 each, covering k-cols (l&31)*4..+3 = 128 floats
  // per row across 32 lanes... That is only 128 of 128 cols ✓ (one op/row).
  // So we need 8 row pointers; keep them but pack as 4 pairs stepping 2*lda.

  // LDS write offsets (b64): row r = w*16 + q*2 + (l>>5),
  // byte = r*256 + ((l&31)*8 ^ ((r&7)<<4))
  int awoff[8];
#pragma unroll
  for (int q = 0; q < 8; ++q) {
    const int r = w * 16 + q * 2 + (l >> 5);
    awoff[q] = r * 256 + ((((l & 31) * 8)) ^ ((r & 7) << 4));
  }

  // fragment read offsets: aoff(af,ak) = af*4096 + aoffb[ak]
  // (since (r&7) = (l&7) is af-independent)
  int aoffb[4];
#pragma unroll
  for (int ak = 0; ak < 4; ++ak)
    aoffb[ak] = (l & 15) * 256 +
                ((ak * 64 + (l >> 4) * 16) ^ ((l & 7) << 4));

  const char* pBw = (const char*)Bp + w * 8192 + l * 16;

  f32x4 acc[8][2] = {};
  f32x4 pA[8];
  bf16x8 Ba[2][4], Bb[2][4];

#define LOAD_PA(KA)                                                           \
  {                                                                           \
    _Pragma("unroll") for (int j = 0; j < 4; ++j) {                           \
      pA[2 * j] = __builtin_nontemporal_load((const f32x4*)(gAr[j] + (KA)));  \
      pA[2 * j + 1] = __builtin_nontemporal_load(                             \
          (const f32x4*)(gAr[j] + (size_t)2 * lda * 4 / 4 * 0 + 0) + 0);      \
    }                                                                         \
  }
#undef LOAD_PA
  // (macro above unused — rows are 8 distinct; use explicit pointer array)
  const float* gAq[8];
#pragma unroll
  for (int q = 0; q < 8; ++q)
    gAq[q] = A + (size_t)(m0 + w * 16 + q * 2 + (l >> 5)) * (size_t)lda +
             (size_t)ts0 * BK + (l & 31) * 4;

  // ---------------- prologue ----------------
#pragma unroll
  for (int q = 0; q < 8; ++q)
    pA[q] = __builtin_nontemporal_load((const f32x4*)gAq[q]);
  SCHED0;
#pragma unroll
  for (int bfi = 0; bfi < 2; ++bfi)
#pragma unroll
    for (int ak = 0; ak < 4; ++ak)
      Ba[bfi][ak] = *(const bf16x8*)(pBw + ((size_t)ts0 << 16) +
                                     (bfi * 4 + ak) * 1024);
  SCHED0;
#pragma unroll
  for (int q = 0; q < 8; ++q) {
    bf16x4 pk;
#pragma unroll
    for (int e = 0; e < 4; ++e) pk[e] = (bf16)pA[q][e];
    *(bf16x4*)(lds[0] + awoff[q]) = pk;
  }
  SCHED0;
  {
    const int s1 = (nsteps > 1) ? BK : 0;
#pragma unroll
    for (int q = 0; q < 8; ++q)
      pA[q] = __builtin_nontemporal_load((const f32x4*)(gAq[q] + s1));
  }
  asm volatile("s_waitcnt lgkmcnt(0)" ::: "memory");
  SBAR;
  SCHED0;

  // ---------------- main loop (x2 unrolled, static indices) ----------------
  // BODY(S, PAR, BCUR, BNXT): rslot=lds[PAR] holds A(S); pA holds A(S+1).
  // 1. ds_write pA -> lds[PAR^1]; 2. B(S+1)->BNXT; 3. A(S+2)->pA;
  // 4. MFMA(A(S) x BCUR); drain lgkm; barrier.
#define BODY_K(S, PAR, BCUR, BNXT)                                            \
  {                                                                           \
    const char* rslot = lds[PAR];                                             \
    char* wslot = lds[PAR ^ 1];                                               \
    _Pragma("unroll") for (int q = 0; q < 8; ++q) {                           \
      bf16x4 pk;                                                              \
      _Pragma("unroll") for (int e = 0; e < 4; ++e) pk[e] = (bf16)pA[q][e];   \
      *(bf16x4*)(wslot + awoff[q]) = pk;                                      \
    }                                                                         \
    SCHED0;                                                                   \
    {                                                                         \
      const int tn = ((S) + 1 < nsteps) ? ts0 + (S) + 1 : ts0;                \
      _Pragma("unroll") for (int bfi = 0; bfi < 2; ++bfi)                     \
          _Pragma("unroll") for (int ak = 0; ak < 4; ++ak)                    \
              BNXT[bfi][ak] = *(const bf16x8*)(                               \
                  pBw + ((size_t)tn << 16) + (bfi * 4 + ak) * 1024);          \
    }                                                                         \
    SCHED0;                                                                   \
    {                                                                         \
      const int ka = ((S) + 2 < nsteps) ? ((S) + 2) * BK : 0;                 \
      _Pragma("unroll") for (int q = 0; q < 8; ++q)                           \
          pA[q] = __builtin_nontemporal_load((const f32x4*)(gAq[q] + ka));    \
    }                                                                         \
    SCHED0;                                                                   \
    __builtin_amdgcn_s_setprio(1);                                            \
    _Pragma("unroll") for (int ak = 0; ak < 4; ++ak) {                        \
      bf16x8 afr[8];                                                          \
      _Pragma("unroll") for (int af = 0; af < 8; ++af)                        \
          afr[af] = *(const bf16x8*)(rslot + af * 4096 + aoffb[ak]);          \
      _Pragma("unroll") for (int af = 0; af < 8; ++af)                        \
          _Pragma("unroll") for (int bfi = 0; bfi < 2; ++bfi)                 \
              acc[af][bfi] = __builtin_amdgcn_mfma_f32_16x16x32_bf16(         \
                  afr[af], BCUR[bfi][ak], acc[af][bfi], 0, 0, 0);             \
    }                                                                         \
    __builtin_amdgcn_s_setprio(0);                                            \
    SCHED0;                                                                   \
    asm volatile("s_waitcnt lgkmcnt(0)" ::: "memory");                        \
    SBAR;                                                                     \
    SCHED0;                                                                   \
  }

  for (int s = 0; s < nsteps; s += 2) {
    BODY_K(s, 0, Ba, Bb);
    BODY_K(s + 1, 1, Bb, Ba);
  }
#undef BODY_K

  // ---------------- epilogue: fp32 partial [8192][256] ----------------
#pragma unroll
  for (int af = 0; af < 8; ++af)
#pragma unroll
    for (int bfi = 0; bfi < 2; ++bfi) {
      const int mb = m0 + af * 16 + (l >> 4) * 4;
      const int n = w * 32 + bfi * 16 + (l & 15);
#pragma unroll
      for (int j = 0; j < 4; ++j)
        Ps[(size_t)(mb + j) * NOUT + n] = acc[af][bfi][j];
    }
}

// reduce2: Fp[m][n] (Bp layout bf16) = filt[m] * sum_ks P[ks][m][n]
__global__ void reduce2(const float* __restrict__ wsP,
                        const float* __restrict__ doutP,
                        const float* __restrict__ filt, bf16* __restrict__ Fp,
                        const int KS) {
  const int n = threadIdx.x;
  const int m8 = blockIdx.x;
  bf16x8 pk;
#pragma unroll
  for (int r = 0; r < 8; ++r) {
    const int m = m8 * 8 + r;
    float s = doutP[(size_t)m * NOUT + n];
    for (int ks = 0; ks < KS - 1; ++ks)
      s += wsP[(size_t)ks * 2097152 + (size_t)m * NOUT + n];
    pk[r] = (bf16)(s * filt[m]);
  }
  const int ts = m8 >> 4, wq = n >> 5, bq = (n >> 4) & 1, aq = (m8 >> 2) & 3;
  const int lq = (m8 & 3) * 16 + (n & 15);
  *(bf16x8*)((char*)Fp +
             (size_t)(((ts * 64 + wq * 8 + bq * 4 + aq) << 10) + lq * 16)) = pk;
}

// reduce3: doutP[i] = sum_ks P[ks][i]
__global__ void reduce3(const float* __restrict__ wsP, float* __restrict__ doutP,
                        const int KS) {
  const size_t i = (size_t)blockIdx.x * 256 + threadIdx.x;
  float s = doutP[i];
  for (int ks = 0; ks < KS - 1; ++ks) s += wsP[(size_t)ks * 2097152 + i];
  doutP[i] = s;
}

// ======================= small-K kernel (round-4 schedule) ==================
template <bool SCALE, bool OUTT>
__global__ __launch_bounds__(NTHREADS, 1) void gemm_small(
    const float* __restrict__ A, const bf16* __restrict__ Bp,
    const float* __restrict__ filt, void* __restrict__ outp,
    const int K, const int lda) {
  __shared__ char lds[2][LDS_SMALL];
  const int t = threadIdx.x;
  const int w = t >> 6;
  const int l = t & 63;
  const int m0 = blockIdx.x * 32;
  const int NT = K / BK;

  const int ar = t >> 4;
  const int acb = t & 15;
  const float* gA = A + (size_t)(m0 + ar) * (size_t)lda + acb * 8;
  const int a_lds_off = (ar * (BK * 2) + acb * 16) ^ ((ar & 7) << 4);

  int aoff[2][4];
#pragma unroll
  for (int af = 0; af < 2; ++af)
#pragma unroll
    for (int ak = 0; ak < 4; ++ak) {
      const int r = af * 16 + (l & 15);
      const int kb = ak * 64 + (l >> 4) * 16;
      aoff[af][ak] = (r * (BK * 2) + kb) ^ ((r & 7) << 4);
    }

  const char* pBw = (const char*)Bp + w * 8192 + l * 16;

  f32x4 acc[2][2] = {};

  f32x4 aS0a = __builtin_nontemporal_load((const f32x4*)gA);
  f32x4 aS0b = __builtin_nontemporal_load((const f32x4*)gA + 1);
  f32x4 aS1a = __builtin_nontemporal_load((const f32x4*)(gA + BK));
  f32x4 aS1b = __builtin_nontemporal_load((const f32x4*)(gA + BK) + 1);
  bf16x8 Bc[2][4], Bn[2][4];
#pragma unroll
  for (int bfi = 0; bfi < 2; ++bfi)
#pragma unroll
    for (int ak = 0; ak < 4; ++ak)
      Bc[bfi][ak] = *(const bf16x8*)(pBw + (bfi * 4 + ak) * 1024);
  {
    bf16x8 pk;
#pragma unroll
    for (int j = 0; j < 4; ++j) { pk[j] = (bf16)aS0a[j]; pk[j + 4] = (bf16)aS0b[j]; }
    *(bf16x8*)(lds[0] + a_lds_off) = pk;
  }
  asm volatile("s_waitcnt lgkmcnt(0)" ::: "memory");
  SBAR;
  SCHED0;

#define BODY_S(TS, P, BCUR, BNXT, AW0, AW1, AL0, AL1)                         \
  {                                                                           \
    const char* bb = lds[P];                                                  \
    bf16x8 afr[2][4];                                                         \
    _Pragma("unroll") for (int af = 0; af < 2; ++af)                          \
        _Pragma("unroll") for (int ak = 0; ak < 4; ++ak)                      \
            afr[af][ak] = *(const bf16x8*)(bb + aoff[af][ak]);                \
    SCHED0;                                                                   \
    const size_t kb1 = (size_t)((((TS) + 1) < NT ? ((TS) + 1) : 0)) << 16;    \
    _Pragma("unroll") for (int bfi = 0; bfi < 2; ++bfi)                       \
        _Pragma("unroll") for (int ak = 0; ak < 4; ++ak)                      \
            BNXT[bfi][ak] =                                                   \
                *(const bf16x8*)(pBw + kb1 + (bfi * 4 + ak) * 1024);          \
    SCHED0;                                                                   \
    const int ka2 = (((TS) + 2) < NT ? ((TS) + 2) : 0) * BK;                  \
    AL0 = __builtin_nontemporal_load((const f32x4*)(gA + ka2));               \
    AL1 = __builtin_nontemporal_load((const f32x4*)(gA + ka2) + 1);           \
    SCHED0;                                                                   \
    asm volatile("s_waitcnt lgkmcnt(0)" ::: "memory");                        \
    SCHED0;                                                                   \
    __builtin_amdgcn_s_setprio(1);                                            \
    _Pragma("unroll") for (int ak = 0; ak < 4; ++ak)                          \
        _Pragma("unroll") for (int af = 0; af < 2; ++af)                      \
            _Pragma("unroll") for (int bfi = 0; bfi < 2; ++bfi)               \
                acc[af][bfi] = __builtin_amdgcn_mfma_f32_16x16x32_bf16(       \
                    afr[af][ak], BCUR[bfi][ak], acc[af][bfi], 0, 0, 0);       \
    __builtin_amdgcn_s_setprio(0);                                            \
    SCHED0;                                                                   \
    {                                                                         \
      bf16x8 pk;                                                              \
      _Pragma("unroll") for (int j = 0; j < 4; ++j) {                         \
        pk[j] = (bf16)AW0[j];                                                 \
        pk[j + 4] = (bf16)AW1[j];                                             \
      }                                                                       \
      *(bf16x8*)(lds[P ^ 1] + a_lds_off) = pk;                                \
    }                                                                         \
    asm volatile("s_waitcnt lgkmcnt(0)" ::: "memory");                        \
    SBAR;                                                                     \
    SCHED0;                                                                   \
  }

  for (int ts = 0; ts < NT; ts += 2) {
    BODY_S(ts, 0, Bc, Bn, aS1a, aS1b, aS0a, aS0b);
    BODY_S(ts + 1, 1, Bn, Bc, aS0a, aS0b, aS1a, aS1b);
  }
#undef BODY_S

#pragma unroll
  for (int af = 0; af < 2; ++af)
#pragma unroll
    for (int bfi = 0; bfi < 2; ++bfi) {
      const int mb = m0 + af * 16 + (l >> 4) * 4;
      const int n = w * 32 + bfi * 16 + (l & 15);
      f32x4 v = acc[af][bfi];
      if (SCALE) {
#pragma unroll
        for (int j = 0; j < 4; ++j) v[j] *= filt[mb + j];
      }
      if (OUTT) {
        bf16x4 pv;
#pragma unroll
        for (int j = 0; j < 4; ++j) pv[j] = (bf16)v[j];
        const int tsq = mb >> 7, wq = n >> 5, bq = (n >> 4) & 1, aq = (mb >> 5) & 3;
        const int lq = ((mb >> 3) & 3) * 16 + (n & 15);
        char* dst = (char*)outp +
                    (size_t)(((tsq * 64 + wq * 8 + bq * 4 + aq) << 10) + lq * 16 +
                             (mb & 7) * 2);
        *(bf16x4*)dst = pv;
      } else {
        float* po = (float*)outp + (size_t)mb * NOUT + n;
#pragma unroll
        for (int j = 0; j < 4; ++j) po[(size_t)j * NOUT] = v[j];
      }
    }
}

// W [256 k][256 n] fp32 -> Wp bf16 in Bp layout
__global__ void prep_wt(const float* __restrict__ W, bf16* __restrict__ Wp) {
  const int k = blockIdx.x;
  const int n = threadIdx.x;
  const int off = (((k >> 7) * 64 + (n >> 5) * 8 + ((n >> 4) & 1) * 4 +
                    ((k >> 5) & 3)) << 10) +
                  (((k >> 3) & 3) * 16 + (n & 15)) * 16 + (k & 7) * 2;
  *(bf16*)((char*)Wp + off) = (bf16)W[k * 256 + n];
}

extern "C" void kernel_launch(void* const* d_in, const int* in_sizes, int n_in,
                              void* d_out, int out_size, void* d_ws, size_t ws_size,
                              hipStream_t stream) {
  const float* features = (const float*)d_in[0];
  const float* wavelets = (const float*)d_in[1];
  const float* wavelets_inv = (const float*)d_in[2];
  const float* W = (const float*)d_in[3];
  const float* filt = (const float*)d_in[4];
  float* out = (float*)d_out;

  char* ws = (char*)d_ws;
  bf16* Wp = (bf16*)ws;                       // 128 KiB
  bf16* Tp = (bf16*)(ws + 131072);            // 4 MiB
  bf16* Fp = (bf16*)(ws + 131072 + 4194304);  // 4 MiB
  float* wsP = (float*)(ws + 131072 + 8388608);  // up to 24 MiB of partials

  const size_t base = 131072 + 8388608;
  int KS = 0, kshift = 0;
  if (ws_size >= base + 3u * 8388608u) { KS = 4; kshift = 2; }
  else if (ws_size >= base + 1u * 8388608u) { KS = 2; kshift = 1; }

  prep_wt<<<256, 256, 0, stream>>>(W, Wp);
  gemm_small<false, true><<<256, NTHREADS, 0, stream>>>(features, Wp, nullptr, Tp, 256, 256);

  if (KS) {
    const int nsteps = 64 / KS;
    gemm_ks<<<64 * KS, NTHREADS, 0, stream>>>(wavelets_inv, Tp, wsP, out, kshift, nsteps, 8192);
    reduce2<<<1024, 256, 0, stream>>>(wsP, out, filt, Fp, KS);
    gemm_ks<<<64 * KS, NTHREADS, 0, stream>>>(wavelets, Fp, wsP, out, kshift, nsteps, 8192);
    reduce3<<<8192, 256, 0, stream>>>(wsP, out, KS);
  } else {
    gemm_ks<<<64, NTHREADS, 0, stream>>>(wavelets_inv, Tp, wsP, out, 0, 64, 8192);
    reduce2<<<1024, 256, 0, stream>>>(wsP, out, filt, Fp, 1);
    gemm_ks<<<64, NTHREADS, 0, stream>>>(wavelets, Fp, wsP, out, 0, 64, 8192);
  }
}